// Round 4
// baseline (2053.787 us; speedup 1.0000x reference)
//
#include <hip/hip_runtime.h>
#include <math.h>

#define DIM 512
#define NSEQ 4096
#define BATCH 4
#define ROWS (BATCH * NSEQ)   // 16384

typedef unsigned long long u64;
typedef unsigned int u32;

// ---------------- top-8 helpers (packed u64 keys) ----------------
// key = ordered_float(score)<<32 | ~index : larger key == larger score; exact
// fp32 ties break toward LOWER index (= np stable argsort desc). key==0 empty.
__device__ __forceinline__ void insert_top8(u64 (&a)[8], u64 key) {
  if (key <= a[7]) return;
  a[7] = key;
#pragma unroll
  for (int i = 7; i > 0; --i) {
    u64 x = a[i - 1], y = a[i];
    u64 hi = x > y ? x : y;
    u64 lo = x > y ? y : x;
    a[i - 1] = hi;
    a[i] = lo;
  }
}

__device__ __forceinline__ float decode_val(u64 key) {
  u32 ord = (u32)(key >> 32);
  u32 s = (ord & 0x80000000u) ? (ord ^ 0x80000000u) : ~ord;
  return __uint_as_float(s);
}

// ------- exact-chain fp32 GEMM: C[M,N] = X[M,K] @ W[K,N] (+bias) (+=) -------
// Per output element: sequential fmaf chain over k ascending == BLAS sgemm
// micro-kernel semantics (bit-identical to np.matmul/OpenBLAS).
__global__ __launch_bounds__(256) void gemm64f(const float* __restrict__ X,
                                               const float* __restrict__ W,
                                               const float* __restrict__ bias,
                                               float* C,
                                               int M, int N, int K, int accum) {
  __shared__ float As[16][68];  // As[k][row]
  __shared__ float Bs[16][68];  // Bs[k][col]
  const int tid = threadIdx.x;
  const int tx = tid & 15, ty = tid >> 4;
  const int n0 = blockIdx.x * 64;
  const int m0 = blockIdx.y * 64;
  const int arow = tid >> 2, ac4 = (tid & 3) * 4;
  const int bkk = tid >> 4, bc4 = (tid & 15) * 4;
  float acc[4][4] = {};
  for (int k0 = 0; k0 < K; k0 += 16) {
    float4 a4 = *(const float4*)(X + (size_t)(m0 + arow) * K + (k0 + ac4));
    float4 b4 = *(const float4*)(W + (size_t)(k0 + bkk) * N + (n0 + bc4));
    As[ac4 + 0][arow] = a4.x;
    As[ac4 + 1][arow] = a4.y;
    As[ac4 + 2][arow] = a4.z;
    As[ac4 + 3][arow] = a4.w;
    *(float4*)&Bs[bkk][bc4] = b4;
    __syncthreads();
#pragma unroll
    for (int kk = 0; kk < 16; ++kk) {
      float4 av = *(const float4*)&As[kk][ty * 4];
      float4 bv = *(const float4*)&Bs[kk][tx * 4];
#pragma unroll
      for (int i = 0; i < 4; ++i) {
        float a = (i == 0) ? av.x : (i == 1) ? av.y : (i == 2) ? av.z : av.w;
        acc[i][0] = fmaf(a, bv.x, acc[i][0]);
        acc[i][1] = fmaf(a, bv.y, acc[i][1]);
        acc[i][2] = fmaf(a, bv.z, acc[i][2]);
        acc[i][3] = fmaf(a, bv.w, acc[i][3]);
      }
    }
    __syncthreads();
  }
  float4 bb = make_float4(0.f, 0.f, 0.f, 0.f);
  if (bias) bb = *(const float4*)(bias + n0 + tx * 4);
#pragma unroll
  for (int i = 0; i < 4; ++i) {
    float* cp = C + (size_t)(m0 + ty * 4 + i) * N + n0 + tx * 4;
    float4 o;
    o.x = acc[i][0] + bb.x;
    o.y = acc[i][1] + bb.y;
    o.z = acc[i][2] + bb.z;
    o.w = acc[i][3] + bb.w;
    if (accum) {
      float4 c0 = *(const float4*)cp;
      o.x += c0.x; o.y += c0.y; o.z += c0.z; o.w += c0.w;
    }
    *(float4*)cp = o;
  }
}

// -------- local message combine: g = 0.25*sum_w silu(A + bm1 + Bv[n-w]) -----
__global__ __launch_bounds__(256) void silu_combine(const float* A,
                                                    const float* Bv,
                                                    const float* bm1,
                                                    float* Gout) {
  size_t idx = (size_t)blockIdx.x * 256 + threadIdx.x;
  int r = (int)(idx >> 7);
  int c4 = (int)(idx & 127);
  int n = r & (NSEQ - 1);
  const float4* A4 = (const float4*)A;
  const float4* B4 = (const float4*)Bv;
  float4 a = A4[(size_t)r * 128 + c4];
  float4 bm = ((const float4*)bm1)[c4];
  float bx = a.x + bm.x, by = a.y + bm.y, bz = a.z + bm.z, bw = a.w + bm.w;
  float sx = 0.f, sy = 0.f, sz = 0.f, sw = 0.f;
#pragma unroll
  for (int w = 1; w <= 4; ++w) {
    float ex = bx, ey = by, ez = bz, ew = bw;
    if (n >= w) {
      float4 nb = B4[(size_t)(r - w) * 128 + c4];
      ex += nb.x; ey += nb.y; ez += nb.z; ew += nb.w;
    }
    sx += ex / (1.f + expf(-ex));
    sy += ey / (1.f + expf(-ey));
    sz += ez / (1.f + expf(-ez));
    sw += ew / (1.f + expf(-ew));
  }
  ((float4*)Gout)[(size_t)r * 128 + c4] =
      make_float4(0.25f * sx, 0.25f * sy, 0.25f * sz, 0.25f * sw);
}

// ---------------- np.einsum-emulating sparse causal attention ----------------
// score(q,m) = AVX512-style dot: 16 strided lane partials (lane = d mod 16,
// sequential fmaf over d/16) + halving-tree reduce (+8,+4,+2,+1), then fp32
// scale. Selection: top-8 on scaled fp32, stable lower-index ties. Softmax:
// fp32 exp, np pairwise-8 sum tree, fp32 divide. Block = 16 queries.
__global__ __launch_bounds__(256) void attn_np(const float* __restrict__ Q,
                                               const float* __restrict__ Kb,
                                               const float* __restrict__ V,
                                               float* __restrict__ G) {
  __shared__ float qs[16][512];
  __shared__ union {
    float S[16][66];
    u64 cand[16][16][8];
  } u;
  __shared__ float psm[16][8];
  __shared__ int pidx[16][8];

  const int tid = threadIdx.x;
  const int bid = blockIdx.x;
  const int b = bid & 3;
  const int ht = bid >> 2;                              // 0..255
  const int qt = (ht < 128) ? (2 * ht) : (511 - 2 * ht);  // load balance
  const int n0 = qt * 16;
  const size_t rb = (size_t)b * NSEQ;

  const int l = tid & 15;         // einsum lane (d mod 16)
  const int mslot = (tid >> 4) & 3;
  const int w = tid >> 6;         // wave id
  const int wm = w * 16 + mslot * 4;  // base m-col of this thread's 4 keys

  // load q tile
  {
    int r = tid & 15, seg = tid >> 4;  // 16 segs x 32 floats
#pragma unroll
    for (int t = 0; t < 8; ++t) {
      float4 v4 = *(const float4*)(Q + ((rb + n0 + r) << 9) + seg * 32 + t * 4);
      qs[r][seg * 32 + t * 4 + 0] = v4.x;
      qs[r][seg * 32 + t * 4 + 1] = v4.y;
      qs[r][seg * 32 + t * 4 + 2] = v4.z;
      qs[r][seg * 32 + t * 4 + 3] = v4.w;
    }
  }
  __syncthreads();

  const float SCALE_F = (float)(1.0 / sqrt(512.0));
  const int qi_s = tid >> 4, sl = tid & 15;  // scan roles
  u64 best[8] = {0, 0, 0, 0, 0, 0, 0, 0};

  const int ntiles = ((n0 + 16) + 63) >> 6;
  for (int mt = 0; mt < ntiles; ++mt) {
    const int m0 = mt << 6;
    float p[16][4] = {};  // [qi][mi] lane partials
    for (int db = 0; db < 512; db += 64) {
      float qreg[16][4];
#pragma unroll
      for (int qi = 0; qi < 16; ++qi)
#pragma unroll
        for (int t = 0; t < 4; ++t) qreg[qi][t] = qs[qi][db + 16 * t + l];
#pragma unroll
      for (int mi = 0; mi < 4; ++mi) {
        const float* kr = Kb + ((rb + m0 + wm + mi) << 9) + db;
        float k0 = kr[l], k1 = kr[16 + l], k2 = kr[32 + l], k3 = kr[48 + l];
#pragma unroll
        for (int qi = 0; qi < 16; ++qi) {
          p[qi][mi] = fmaf(k0, qreg[qi][0], p[qi][mi]);
          p[qi][mi] = fmaf(k1, qreg[qi][1], p[qi][mi]);
          p[qi][mi] = fmaf(k2, qreg[qi][2], p[qi][mi]);
          p[qi][mi] = fmaf(k3, qreg[qi][3], p[qi][mi]);
        }
      }
    }
    // halving-tree reduce across the 16 lanes (bit-exact _mm512_reduce_add_ps)
#pragma unroll
    for (int qi = 0; qi < 16; ++qi) {
#pragma unroll
      for (int mi = 0; mi < 4; ++mi) {
        float r = p[qi][mi];
        r += __shfl_xor(r, 8);
        r += __shfl_xor(r, 4);
        r += __shfl_xor(r, 2);
        r += __shfl_xor(r, 1);
        if (l == qi) u.S[qi][wm + mi] = r * SCALE_F;
      }
    }
    __syncthreads();
    // scan 4 entries per thread into per-thread top-8
#pragma unroll
    for (int j = 0; j < 4; ++j) {
      int mcol = sl * 4 + j;
      int m = m0 + mcol;
      if (m <= n0 + qi_s) {
        float v = u.S[qi_s][mcol];
        u32 sb = __float_as_uint(v);
        u32 ord = sb ^ ((sb >> 31) ? 0xFFFFFFFFu : 0x80000000u);
        u64 key = ((u64)ord << 32) | (u32)(~(u32)m);
        insert_top8(best, key);
      }
    }
    __syncthreads();
  }

  // stash per-thread top-8 (overwrites S space)
#pragma unroll
  for (int i = 0; i < 8; ++i) u.cand[qi_s][sl][i] = best[i];
  __syncthreads();

  if (tid < 16) {  // per-query merge + np-style softmax
    u64 mb[8] = {0, 0, 0, 0, 0, 0, 0, 0};
    for (int s2 = 0; s2 < 16; ++s2)
#pragma unroll
      for (int t2 = 0; t2 < 8; ++t2) insert_top8(mb, u.cand[tid][s2][t2]);
    float vmax = decode_val(mb[0]);
    float e[8];
#pragma unroll
    for (int i = 0; i < 8; ++i)
      e[i] = (mb[i] != 0ULL) ? expf(decode_val(mb[i]) - vmax) : 0.f;
    float s01 = e[0] + e[1], s23 = e[2] + e[3];
    float s45 = e[4] + e[5], s67 = e[6] + e[7];
    float ssum = (s01 + s23) + (s45 + s67);  // np pairwise-8 tree
#pragma unroll
    for (int i = 0; i < 8; ++i) {
      psm[tid][i] = e[i] / ssum;
      pidx[tid][i] = (mb[i] != 0ULL) ? (int)(~(u32)mb[i]) : 0;
    }
  }
  __syncthreads();

  {  // PV gather: 16 threads per query, 32 dims each
    const int qi = tid >> 4, seg = tid & 15;
    float pp[8];
    int ix[8];
#pragma unroll
    for (int i = 0; i < 8; ++i) { pp[i] = psm[qi][i]; ix[i] = pidx[qi][i]; }
    const float4* V4 = (const float4*)V;
    float4* G4 = (float4*)G;
    const size_t ob = ((rb + n0 + qi) << 7) + seg * 8;
#pragma unroll
    for (int it = 0; it < 8; ++it) {
      float4 a = make_float4(0.f, 0.f, 0.f, 0.f);
#pragma unroll
      for (int i = 0; i < 8; ++i) {
        float4 vv = V4[((rb + ix[i]) << 7) + seg * 8 + it];
        a.x = fmaf(pp[i], vv.x, a.x);
        a.y = fmaf(pp[i], vv.y, a.y);
        a.z = fmaf(pp[i], vv.z, a.z);
        a.w = fmaf(pp[i], vv.w, a.w);
      }
      G4[ob + it] = a;
    }
  }
}

extern "C" void kernel_launch(void* const* d_in, const int* in_sizes, int n_in,
                              void* d_out, int out_size, void* d_ws, size_t ws_size,
                              hipStream_t stream) {
  const float* mu = (const float*)d_in[0];
  const float* Wq = (const float*)d_in[1];
  const float* bq = (const float*)d_in[2];
  const float* Wk = (const float*)d_in[3];
  const float* bk = (const float*)d_in[4];
  const float* Wv = (const float*)d_in[5];
  const float* bv = (const float*)d_in[6];
  const float* Wm1 = (const float*)d_in[7];
  const float* bm1 = (const float*)d_in[8];
  const float* Wm2 = (const float*)d_in[9];
  const float* bm2 = (const float*)d_in[10];
  const float* Wo = (const float*)d_in[11];
  const float* bo = (const float*)d_in[12];
  float* out = (float*)d_out;

  float* ws = (float*)d_ws;
  const size_t RD = (size_t)ROWS * DIM;
  float* Qb = ws;       // q  -> later reused for local
  float* Kbf = Qb + RD; // k
  float* Vb = Kbf + RD; // v
  float* Ab = Vb + RD;  // A = mu@Wm1_top  -> overwritten by g
  float* Bb = Ab + RD;  // Bv = mu@Wm1_bot -> overwritten by global msgs

  dim3 blk(256);
  dim3 gbig(DIM / 64, ROWS / 64);

  // projections: exact-chain fp32 (bit-matches np/OpenBLAS sgemm)
  gemm64f<<<gbig, blk, 0, stream>>>(mu, Wq, bq, Qb, ROWS, DIM, DIM, 0);
  gemm64f<<<gbig, blk, 0, stream>>>(mu, Wk, bk, Kbf, ROWS, DIM, DIM, 0);
  gemm64f<<<gbig, blk, 0, stream>>>(mu, Wv, bv, Vb, ROWS, DIM, DIM, 0);
  gemm64f<<<gbig, blk, 0, stream>>>(mu, Wm1, (const float*)nullptr, Ab, ROWS, DIM, DIM, 0);
  gemm64f<<<gbig, blk, 0, stream>>>(mu, Wm1 + (size_t)DIM * DIM, (const float*)nullptr, Bb, ROWS, DIM, DIM, 0);

  // local messages (in-place over Ab; reads Bb)
  silu_combine<<<dim3(ROWS * 128 / 256), blk, 0, stream>>>(Ab, Bb, bm1, Ab);

  // sparse causal attention with np-einsum score emulation (writes Bb)
  attn_np<<<dim3(1024), blk, 0, stream>>>(Qb, Kbf, Vb, Bb);

  // local = g @ Wm2 + bm2   (q dead -> write Qb)
  gemm64f<<<gbig, blk, 0, stream>>>(Ab, Wm2, bm2, Qb, ROWS, DIM, DIM, 0);

  // out = local @ Wo_top + bo ; out += global @ Wo_bot
  gemm64f<<<gbig, blk, 0, stream>>>(Qb, Wo, bo, out, ROWS, DIM, DIM, 0);
  gemm64f<<<gbig, blk, 0, stream>>>(Bb, Wo + (size_t)DIM * DIM, (const float*)nullptr, out, ROWS, DIM, DIM, 1);
}

// Round 5
// 1036.059 us; speedup vs baseline: 1.9823x; 1.9823x over previous
//
#include <hip/hip_runtime.h>
#include <math.h>

#define DIM 512
#define NSEQ 4096
#define BATCH 4
#define ROWS (BATCH * NSEQ)   // 16384

typedef unsigned long long u64;
typedef unsigned int u32;
typedef unsigned short u16;
typedef __attribute__((ext_vector_type(8))) short bf16x8;
typedef __attribute__((ext_vector_type(4))) float f32x4;

// ---------------- bf16 helpers (RNE) ----------------
__device__ __forceinline__ u32 to_bf16(float f) {
  u32 x = __float_as_uint(f);
  return (x + 0x7fffu + ((x >> 16) & 1u)) >> 16;
}
__device__ __forceinline__ u32 pk2(float a, float b) {
  return to_bf16(a) | (to_bf16(b) << 16);
}
__device__ __forceinline__ uint4 pk8(float4 a, float4 b) {
  return make_uint4(pk2(a.x, a.y), pk2(a.z, a.w), pk2(b.x, b.y), pk2(b.z, b.w));
}

// ---------------- top-N helpers (packed u64 keys) ----------------
// key = ordered_float(score)<<32 | ~index : larger key == larger score; exact
// fp32 ties break toward LOWER index (= np stable top_k). key==0 empty.
__device__ __forceinline__ void insert_top8(u64 (&a)[8], u64 key) {
  if (key <= a[7]) return;
  a[7] = key;
#pragma unroll
  for (int i = 7; i > 0; --i) {
    u64 x = a[i - 1], y = a[i];
    u64 hi = x > y ? x : y;
    u64 lo = x > y ? y : x;
    a[i - 1] = hi;
    a[i] = lo;
  }
}
template<int NN>
__device__ __forceinline__ void insert_topN(u64 (&a)[NN], u64 key) {
  if (key <= a[NN - 1]) return;
  a[NN - 1] = key;
#pragma unroll
  for (int i = NN - 1; i > 0; --i) {
    u64 x = a[i - 1], y = a[i];
    u64 hi = x > y ? x : y;
    u64 lo = x > y ? y : x;
    a[i - 1] = hi;
    a[i] = lo;
  }
}
__device__ __forceinline__ float decode_val(u64 key) {
  u32 ord = (u32)(key >> 32);
  u32 s = (ord & 0x80000000u) ? (ord ^ 0x80000000u) : ~ord;
  return __uint_as_float(s);
}
__device__ __forceinline__ u64 pack_key(float v, int m) {
  u32 sb = __float_as_uint(v);
  u32 ord = sb ^ ((sb >> 31) ? 0xFFFFFFFFu : 0x80000000u);
  return ((u64)ord << 32) | (u32)(~(u32)m);
}

// ------- exact-chain fp32 GEMM (np/OpenBLAS-bit-exact) — q,k only -------
__global__ __launch_bounds__(256) void gemm64f(const float* __restrict__ X,
                                               const float* __restrict__ W,
                                               const float* __restrict__ bias,
                                               float* C,
                                               int M, int N, int K, int accum) {
  __shared__ float As[16][68];
  __shared__ float Bs[16][68];
  const int tid = threadIdx.x;
  const int tx = tid & 15, ty = tid >> 4;
  const int n0 = blockIdx.x * 64;
  const int m0 = blockIdx.y * 64;
  const int arow = tid >> 2, ac4 = (tid & 3) * 4;
  const int bkk = tid >> 4, bc4 = (tid & 15) * 4;
  float acc[4][4] = {};
  for (int k0 = 0; k0 < K; k0 += 16) {
    float4 a4 = *(const float4*)(X + (size_t)(m0 + arow) * K + (k0 + ac4));
    float4 b4 = *(const float4*)(W + (size_t)(k0 + bkk) * N + (n0 + bc4));
    As[ac4 + 0][arow] = a4.x;
    As[ac4 + 1][arow] = a4.y;
    As[ac4 + 2][arow] = a4.z;
    As[ac4 + 3][arow] = a4.w;
    *(float4*)&Bs[bkk][bc4] = b4;
    __syncthreads();
#pragma unroll
    for (int kk = 0; kk < 16; ++kk) {
      float4 av = *(const float4*)&As[kk][ty * 4];
      float4 bv = *(const float4*)&Bs[kk][tx * 4];
#pragma unroll
      for (int i = 0; i < 4; ++i) {
        float a = (i == 0) ? av.x : (i == 1) ? av.y : (i == 2) ? av.z : av.w;
        acc[i][0] = fmaf(a, bv.x, acc[i][0]);
        acc[i][1] = fmaf(a, bv.y, acc[i][1]);
        acc[i][2] = fmaf(a, bv.z, acc[i][2]);
        acc[i][3] = fmaf(a, bv.w, acc[i][3]);
      }
    }
    __syncthreads();
  }
  float4 bb = make_float4(0.f, 0.f, 0.f, 0.f);
  if (bias) bb = *(const float4*)(bias + n0 + tx * 4);
#pragma unroll
  for (int i = 0; i < 4; ++i) {
    float* cp = C + (size_t)(m0 + ty * 4 + i) * N + n0 + tx * 4;
    float4 o;
    o.x = acc[i][0] + bb.x;
    o.y = acc[i][1] + bb.y;
    o.z = acc[i][2] + bb.z;
    o.w = acc[i][3] + bb.w;
    if (accum) {
      float4 c0 = *(const float4*)cp;
      o.x += c0.x; o.y += c0.y; o.z += c0.z; o.w += c0.w;
    }
    *(float4*)cp = o;
  }
}

// ---------------- weight transpose+convert: WT[n][k] = bf16(W[k][n]) --------
__global__ __launch_bounds__(256) void wtrans(const float* __restrict__ src,
                                              u16* __restrict__ dst) {
  int o = blockIdx.x * 256 + threadIdx.x;  // 65536 total, 4 outputs each
  int n = o >> 7;
  int k0 = (o & 127) * 4;
  float a0 = src[(size_t)(k0 + 0) * DIM + n];
  float a1 = src[(size_t)(k0 + 1) * DIM + n];
  float a2 = src[(size_t)(k0 + 2) * DIM + n];
  float a3 = src[(size_t)(k0 + 3) * DIM + n];
  ((uint2*)dst)[(n << 7) + (k0 >> 2)] = make_uint2(pk2(a0, a1), pk2(a2, a3));
}

// ---------------- fp32 -> bf16 convert (8 elems/thread) ----------------
__global__ __launch_bounds__(256) void convbf(const float* __restrict__ src,
                                              u16* __restrict__ dst) {
  int o = blockIdx.x * 256 + threadIdx.x;
  const float4* s4 = (const float4*)src;
  float4 a = s4[o * 2], b = s4[o * 2 + 1];
  ((uint4*)dst)[o] = pk8(a, b);
}

// ---------------- bf16 MFMA GEMM: C[16384,512] = A[.,512] @ W[512,512] ------
// WT is [N][K] bf16 (pre-transposed). A fp32 converted in staging.
__global__ __launch_bounds__(256) void gemmbf(const float* __restrict__ A,
                                              const u16* __restrict__ WT,
                                              const float* __restrict__ bias,
                                              float* C, int accum) {
  __shared__ u16 As[128 * 32];   // [row][k] swizzled: slot ^= (row>>1)&3
  __shared__ u16 Bs[128 * 32];   // [col][k] swizzled
  const int tid = threadIdx.x;
  const int n0 = blockIdx.x * 128;
  const int m0 = blockIdx.y * 128;
  const int l = tid & 63, lr = l & 15, lu = l >> 4;
  const int wid = tid >> 6, wr = wid >> 1, wc = wid & 1;
  const int srow = tid >> 1, shalf = tid & 1;
  f32x4 acc[4][4] = {};
  for (int k0 = 0; k0 < 512; k0 += 32) {
    __syncthreads();
    {  // stage A: 16 fp32 -> 16 bf16
      const float4* a4 = (const float4*)(A + (size_t)(m0 + srow) * 512 + k0 + shalf * 16);
      float4 u0 = a4[0], u1 = a4[1], u2 = a4[2], u3 = a4[3];
      int sw = (srow >> 1) & 3;
      *(uint4*)&As[srow * 32 + ((shalf * 2 + 0) ^ sw) * 8] = pk8(u0, u1);
      *(uint4*)&As[srow * 32 + ((shalf * 2 + 1) ^ sw) * 8] = pk8(u2, u3);
    }
    {  // stage B: copy bf16
      const uint4* b4 = (const uint4*)(WT + (size_t)(n0 + srow) * 512 + k0 + shalf * 16);
      uint4 v0 = b4[0], v1 = b4[1];
      int sw = (srow >> 1) & 3;
      *(uint4*)&Bs[srow * 32 + ((shalf * 2 + 0) ^ sw) * 8] = v0;
      *(uint4*)&Bs[srow * 32 + ((shalf * 2 + 1) ^ sw) * 8] = v1;
    }
    __syncthreads();
    bf16x8 af[4], bf_[4];
#pragma unroll
    for (int fr = 0; fr < 4; ++fr) {
      int row = wr * 64 + fr * 16 + lr;
      af[fr] = *(const bf16x8*)&As[row * 32 + (lu ^ ((row >> 1) & 3)) * 8];
    }
#pragma unroll
    for (int fc = 0; fc < 4; ++fc) {
      int col = wc * 64 + fc * 16 + lr;
      bf_[fc] = *(const bf16x8*)&Bs[col * 32 + (lu ^ ((col >> 1) & 3)) * 8];
    }
#pragma unroll
    for (int fr = 0; fr < 4; ++fr)
#pragma unroll
      for (int fc = 0; fc < 4; ++fc)
        acc[fr][fc] = __builtin_amdgcn_mfma_f32_16x16x32_bf16(af[fr], bf_[fc], acc[fr][fc], 0, 0, 0);
  }
#pragma unroll
  for (int fr = 0; fr < 4; ++fr)
#pragma unroll
    for (int fc = 0; fc < 4; ++fc) {
      int col = n0 + wc * 64 + fc * 16 + lr;
      float bb = bias ? bias[col] : 0.f;
#pragma unroll
      for (int j = 0; j < 4; ++j) {
        int row = m0 + wr * 64 + fr * 16 + lu * 4 + j;
        size_t off = (size_t)row * 512 + col;
        float o = acc[fr][fc][j] + bb;
        if (accum) o += C[off];
        C[off] = o;
      }
    }
}

// -------- local message combine: g = 0.25*sum_w silu(A + bm1 + Bv[n-w]) -----
__global__ __launch_bounds__(256) void silu_combine(const float* A,
                                                    const float* Bv,
                                                    const float* bm1,
                                                    float* Gout) {
  size_t idx = (size_t)blockIdx.x * 256 + threadIdx.x;
  int r = (int)(idx >> 7);
  int c4 = (int)(idx & 127);
  int n = r & (NSEQ - 1);
  const float4* A4 = (const float4*)A;
  const float4* B4 = (const float4*)Bv;
  float4 a = A4[(size_t)r * 128 + c4];
  float4 bm = ((const float4*)bm1)[c4];
  float bx = a.x + bm.x, by = a.y + bm.y, bz = a.z + bm.z, bw = a.w + bm.w;
  float sx = 0.f, sy = 0.f, sz = 0.f, sw = 0.f;
#pragma unroll
  for (int w = 1; w <= 4; ++w) {
    float ex = bx, ey = by, ez = bz, ew = bw;
    if (n >= w) {
      float4 nb = B4[(size_t)(r - w) * 128 + c4];
      ex += nb.x; ey += nb.y; ez += nb.z; ew += nb.w;
    }
    sx += ex / (1.f + expf(-ex));
    sy += ey / (1.f + expf(-ey));
    sz += ez / (1.f + expf(-ez));
    sw += ew / (1.f + expf(-ew));
  }
  ((float4*)Gout)[(size_t)r * 128 + c4] =
      make_float4(0.25f * sx, 0.25f * sy, 0.25f * sz, 0.25f * sw);
}

// ---------------- MFMA candidate-gen + exact np rescore attention -----------
// Block = 32 queries of one batch, 256 thr (4 waves). bf16 MFMA QK^T streams
// 128-key tiles -> per-(query,slice) top-16 (bf16 order) -> merged top-16 ->
// in-thread exact np-chain rescore -> exact top-8 + softmax + PV.
union AttnU {
  float S[32][132];
  u64 cand[256][16];
};

__global__ __launch_bounds__(256) void attn_mfma(const float* __restrict__ Qf,
                                                 const float* __restrict__ Kf,
                                                 const u16* __restrict__ Kbf,
                                                 const float* __restrict__ V,
                                                 float* __restrict__ G) {
  __shared__ u16 Qs[32 * 512];   // [q][k] swizzled: slot ^= row&7   (32 KB)
  __shared__ u16 Ks[128 * 32];   // [key][k] swizzled: slot ^= (key>>1)&3 (8 KB)
  __shared__ AttnU un;           // 32 KB
  __shared__ int cidx[32][16];
  __shared__ u64 exkey[32][16];
  __shared__ float psm[32][8];
  __shared__ int pidx[32][8];

  const int tid = threadIdx.x;
  const int bid = blockIdx.x;
  const int b = bid & 3;
  const int h = bid >> 2;                        // 0..127
  const int qt = (h < 64) ? 2 * h : 255 - 2 * h; // load-balance pairing
  const int n0 = qt * 32;
  const size_t rb = (size_t)b * NSEQ;
  const float SCALE_F = 0.04419417382415922f;    // (float)(1/sqrt(512))

  const int l = tid & 63, lr = l & 15, lu = l >> 4;
  const int wid = tid >> 6;
  const int wkey = wid * 32;

  // ---- stage Q block fp32->bf16, swizzled ----
  {
    int row = tid >> 3, part = tid & 7;
    const float4* src = (const float4*)(Qf + ((rb + n0 + row) << 9));
#pragma unroll
    for (int c = 0; c < 8; ++c) {
      int slot = part * 8 + c;
      float4 x = src[slot * 2], y = src[slot * 2 + 1];
      *(uint4*)&Qs[row * 512 + (slot ^ (row & 7)) * 8] = pk8(x, y);
    }
  }

  u64 best[16] = {};
  const int qi_s = tid >> 3, sl = tid & 7;
  const int nq = n0 + qi_s;

  const int nkt = (n0 + 32 + 127) >> 7;
  for (int kt = 0; kt < nkt; ++kt) {
    const int m0 = kt << 7;
    f32x4 acc[2][2] = {};
    for (int k0 = 0; k0 < 512; k0 += 32) {
      __syncthreads();
      {  // stage K tile (128 keys x 32 k) bf16 copy, swizzled
        int key = tid >> 1, half = tid & 1;
        const u16* krow = Kbf + ((rb + m0 + key) << 9) + k0;
        int sw = (key >> 1) & 3;
#pragma unroll
        for (int c = 0; c < 2; ++c) {
          uint4 v = *(const uint4*)(krow + (half * 2 + c) * 8);
          *(uint4*)&Ks[key * 32 + ((half * 2 + c) ^ sw) * 8] = v;
        }
      }
      __syncthreads();
      bf16x8 af[2], bf_[2];
#pragma unroll
      for (int fq = 0; fq < 2; ++fq) {
        int row = fq * 16 + lr;
        af[fq] = *(const bf16x8*)&Qs[row * 512 + (((k0 >> 3) + lu) ^ (row & 7)) * 8];
      }
#pragma unroll
      for (int fk = 0; fk < 2; ++fk) {
        int key = wkey + fk * 16 + lr;
        bf_[fk] = *(const bf16x8*)&Ks[key * 32 + (lu ^ ((key >> 1) & 3)) * 8];
      }
#pragma unroll
      for (int fq = 0; fq < 2; ++fq)
#pragma unroll
        for (int fk = 0; fk < 2; ++fk)
          acc[fq][fk] = __builtin_amdgcn_mfma_f32_16x16x32_bf16(af[fq], bf_[fk], acc[fq][fk], 0, 0, 0);
    }
    // write scores to LDS
#pragma unroll
    for (int fq = 0; fq < 2; ++fq)
#pragma unroll
      for (int fk = 0; fk < 2; ++fk)
#pragma unroll
        for (int j = 0; j < 4; ++j)
          un.S[fq * 16 + lu * 4 + j][wkey + fk * 16 + lr] = acc[fq][fk][j];
    __syncthreads();
    // scan: per (query, slice) streaming top-16 in bf16 ordering
#pragma unroll
    for (int j = 0; j < 16; ++j) {
      int m = m0 + sl * 16 + j;
      if (m <= nq) insert_topN<16>(best, pack_key(un.S[qi_s][sl * 16 + j], m));
    }
    __syncthreads();
  }

  // stash per-thread candidates (S region dead)
#pragma unroll
  for (int i = 0; i < 16; ++i) un.cand[tid][i] = best[i];
  __syncthreads();

  // merge 8 slices -> per-query bf16 top-16 candidate indices
  if (tid < 32) {
    u64 mb[16] = {};
    for (int s2 = 0; s2 < 8; ++s2)
#pragma unroll
      for (int t2 = 0; t2 < 16; ++t2) insert_topN<16>(mb, un.cand[tid * 8 + s2][t2]);
#pragma unroll
    for (int i = 0; i < 16; ++i)
      cidx[tid][i] = (mb[i] != 0ULL) ? (int)(~(u32)mb[i]) : -1;
  }
  __syncthreads();

  // ---- exact np-chain rescore of <=16 candidates per query ----
  {
    const int qi = tid >> 3, cp = tid & 7;
    const float4* q4 = (const float4*)(Qf + ((rb + n0 + qi) << 9));
#pragma unroll
    for (int cc = 0; cc < 2; ++cc) {
      int c = cp * 2 + cc;
      int ci = cidx[qi][c];
      u64 key = 0;
      if (ci >= 0) {
        const float4* k4 = (const float4*)(Kf + ((rb + ci) << 9));
        float p[16] = {};
#pragma unroll 4
        for (int t = 0; t < 128; ++t) {
          float4 qv = q4[t], kv = k4[t];
          int j = (t & 3) * 4;
          p[j + 0] = fmaf(qv.x, kv.x, p[j + 0]);
          p[j + 1] = fmaf(qv.y, kv.y, p[j + 1]);
          p[j + 2] = fmaf(qv.z, kv.z, p[j + 2]);
          p[j + 3] = fmaf(qv.w, kv.w, p[j + 3]);
        }
#pragma unroll
        for (int s = 8; s >= 1; s >>= 1)
#pragma unroll
          for (int jj = 0; jj < 8; ++jj)
            if (jj < s) p[jj] = p[jj] + p[jj + s];
        key = pack_key(p[0] * SCALE_F, ci);
      }
      exkey[qi][c] = key;
    }
  }
  __syncthreads();

  // ---- exact top-8 + np softmax ----
  if (tid < 32) {
    u64 mb[8] = {};
#pragma unroll
    for (int t2 = 0; t2 < 16; ++t2) insert_top8(mb, exkey[tid][t2]);
    float vmax = decode_val(mb[0]);
    float e[8];
#pragma unroll
    for (int i = 0; i < 8; ++i)
      e[i] = (mb[i] != 0ULL) ? expf(decode_val(mb[i]) - vmax) : 0.f;
    float s01 = e[0] + e[1], s23 = e[2] + e[3];
    float s45 = e[4] + e[5], s67 = e[6] + e[7];
    float ssum = (s01 + s23) + (s45 + s67);  // np pairwise-8 tree
#pragma unroll
    for (int i = 0; i < 8; ++i) {
      psm[tid][i] = e[i] / ssum;
      pidx[tid][i] = (mb[i] != 0ULL) ? (int)(~(u32)mb[i]) : 0;
    }
  }
  __syncthreads();

  // ---- PV gather: 8 threads per query, 64 dims each ----
  {
    const int qi = tid >> 3, seg = tid & 7;
    float pp[8];
    int ix[8];
#pragma unroll
    for (int i = 0; i < 8; ++i) { pp[i] = psm[qi][i]; ix[i] = pidx[qi][i]; }
    const float4* V4 = (const float4*)V;
    float4* G4 = (float4*)G;
    const size_t ob = ((rb + n0 + qi) << 7) + seg * 16;
#pragma unroll
    for (int it = 0; it < 16; ++it) {
      float4 a = make_float4(0.f, 0.f, 0.f, 0.f);
#pragma unroll
      for (int i = 0; i < 8; ++i) {
        float4 vv = V4[((rb + ix[i]) << 7) + seg * 16 + it];
        a.x = fmaf(pp[i], vv.x, a.x);
        a.y = fmaf(pp[i], vv.y, a.y);
        a.z = fmaf(pp[i], vv.z, a.z);
        a.w = fmaf(pp[i], vv.w, a.w);
      }
      G4[ob + it] = a;
    }
  }
}

extern "C" void kernel_launch(void* const* d_in, const int* in_sizes, int n_in,
                              void* d_out, int out_size, void* d_ws, size_t ws_size,
                              hipStream_t stream) {
  const float* mu = (const float*)d_in[0];
  const float* Wq = (const float*)d_in[1];
  const float* bq = (const float*)d_in[2];
  const float* Wk = (const float*)d_in[3];
  const float* bk = (const float*)d_in[4];
  const float* Wv = (const float*)d_in[5];
  const float* bv = (const float*)d_in[6];
  const float* Wm1 = (const float*)d_in[7];
  const float* bm1 = (const float*)d_in[8];
  const float* Wm2 = (const float*)d_in[9];
  const float* bm2 = (const float*)d_in[10];
  const float* Wo = (const float*)d_in[11];
  const float* bo = (const float*)d_in[12];
  float* out = (float*)d_out;

  float* ws = (float*)d_ws;
  const size_t RD = (size_t)ROWS * DIM;
  const size_t DD = (size_t)DIM * DIM;
  float* X1 = ws;            // q           -> later A, g
  float* X2 = X1 + RD;       // k           -> later Bv
  float* X3 = X2 + RD;       // v           -> later local
  float* X4 = X3 + RD;       // global msgs
  u16* Kbf = (u16*)(X4 + RD);          // RD bf16
  u16* WT = Kbf + RD;                  // 6 x 512x512 bf16
  u16* WvT = WT;
  u16* Wm1aT = WT + DD;
  u16* Wm1bT = WT + 2 * DD;
  u16* Wm2T = WT + 3 * DD;
  u16* WoTT = WT + 4 * DD;
  u16* WoBT = WT + 5 * DD;

  dim3 blk(256);
  dim3 gex(DIM / 64, ROWS / 64);
  dim3 gbf(DIM / 128, ROWS / 128);

  // weight transposes (bf16)
  wtrans<<<dim3(256), blk, 0, stream>>>(Wv, WvT);
  wtrans<<<dim3(256), blk, 0, stream>>>(Wm1, Wm1aT);
  wtrans<<<dim3(256), blk, 0, stream>>>(Wm1 + DD, Wm1bT);
  wtrans<<<dim3(256), blk, 0, stream>>>(Wm2, Wm2T);
  wtrans<<<dim3(256), blk, 0, stream>>>(Wo, WoTT);
  wtrans<<<dim3(256), blk, 0, stream>>>(Wo + DD, WoBT);

  // q,k: exact-chain fp32 (np-bit-exact, feeds selection)
  gemm64f<<<gex, blk, 0, stream>>>(mu, Wq, bq, X1, ROWS, DIM, DIM, 0);
  gemm64f<<<gex, blk, 0, stream>>>(mu, Wk, bk, X2, ROWS, DIM, DIM, 0);
  convbf<<<dim3((int)(RD / 8 / 256)), blk, 0, stream>>>(X2, Kbf);

  // v (bf16 MFMA; value-path precision is ample)
  gemmbf<<<gbf, blk, 0, stream>>>(mu, WvT, bv, X3, 0);

  // sparse causal attention -> X4
  attn_mfma<<<dim3(512), blk, 0, stream>>>(X1, X2, Kbf, X3, X4);

  // local path (q,k,v buffers now dead -> reuse)
  gemmbf<<<gbf, blk, 0, stream>>>(mu, Wm1aT, (const float*)nullptr, X1, 0);
  gemmbf<<<gbf, blk, 0, stream>>>(mu, Wm1bT, (const float*)nullptr, X2, 0);
  silu_combine<<<dim3(ROWS * 128 / 256), blk, 0, stream>>>(X1, X2, bm1, X1);
  gemmbf<<<gbf, blk, 0, stream>>>(X1, Wm2T, bm2, X3, 0);

  // out = local @ Wo_top + bo ; out += global @ Wo_bot
  gemmbf<<<gbf, blk, 0, stream>>>(X3, WoTT, bo, out, 0);
  gemmbf<<<gbf, blk, 0, stream>>>(X4, WoBT, (const float*)nullptr, out, 1);
}

// Round 6
// 1034.540 us; speedup vs baseline: 1.9852x; 1.0015x over previous
//
#include <hip/hip_runtime.h>
#include <math.h>

#define DIM 512
#define NSEQ 4096
#define BATCH 4
#define ROWS (BATCH * NSEQ)   // 16384

typedef unsigned long long u64;
typedef unsigned int u32;
typedef unsigned short u16;
typedef __attribute__((ext_vector_type(8))) short bf16x8;
typedef __attribute__((ext_vector_type(4))) float f32x4;

// ---------------- bf16 helpers (RNE) ----------------
__device__ __forceinline__ u32 to_bf16(float f) {
  u32 x = __float_as_uint(f);
  return (x + 0x7fffu + ((x >> 16) & 1u)) >> 16;
}
__device__ __forceinline__ u32 pk2(float a, float b) {
  return to_bf16(a) | (to_bf16(b) << 16);
}
__device__ __forceinline__ uint4 pk8(float4 a, float4 b) {
  return make_uint4(pk2(a.x, a.y), pk2(a.z, a.w), pk2(b.x, b.y), pk2(b.z, b.w));
}

// ---------------- top-N helpers (packed u64 keys) ----------------
// key = ordered_float(score)<<32 | ~index : larger key == larger score; exact
// fp32 ties break toward LOWER index (= np stable top_k). key==0 empty.
__device__ __forceinline__ void insert_top8(u64 (&a)[8], u64 key) {
  if (key <= a[7]) return;
  a[7] = key;
#pragma unroll
  for (int i = 7; i > 0; --i) {
    u64 x = a[i - 1], y = a[i];
    u64 hi = x > y ? x : y;
    u64 lo = x > y ? y : x;
    a[i - 1] = hi;
    a[i] = lo;
  }
}
template<int NN>
__device__ __forceinline__ void insert_topN(u64 (&a)[NN], u64 key) {
  if (key <= a[NN - 1]) return;
  a[NN - 1] = key;
#pragma unroll
  for (int i = NN - 1; i > 0; --i) {
    u64 x = a[i - 1], y = a[i];
    u64 hi = x > y ? x : y;
    u64 lo = x > y ? y : x;
    a[i - 1] = hi;
    a[i] = lo;
  }
}
__device__ __forceinline__ float decode_val(u64 key) {
  u32 ord = (u32)(key >> 32);
  u32 s = (ord & 0x80000000u) ? (ord ^ 0x80000000u) : ~ord;
  return __uint_as_float(s);
}
__device__ __forceinline__ u64 pack_key(float v, int m) {
  u32 sb = __float_as_uint(v);
  u32 ord = sb ^ ((sb >> 31) ? 0xFFFFFFFFu : 0x80000000u);
  return ((u64)ord << 32) | (u32)(~(u32)m);
}

// ------- exact-chain fp32 GEMM (np/OpenBLAS-bit-exact) — q,k only -------
// Optional Cbf: also emit bf16(o) (fuses the k->bf16 convert pass).
__global__ __launch_bounds__(256) void gemm64f(const float* __restrict__ X,
                                               const float* __restrict__ W,
                                               const float* __restrict__ bias,
                                               float* C, u16* Cbf,
                                               int M, int N, int K) {
  __shared__ float As[16][68];
  __shared__ float Bs[16][68];
  const int tid = threadIdx.x;
  const int tx = tid & 15, ty = tid >> 4;
  const int n0 = blockIdx.x * 64;
  const int m0 = blockIdx.y * 64;
  const int arow = tid >> 2, ac4 = (tid & 3) * 4;
  const int bkk = tid >> 4, bc4 = (tid & 15) * 4;
  float acc[4][4] = {};
  for (int k0 = 0; k0 < K; k0 += 16) {
    float4 a4 = *(const float4*)(X + (size_t)(m0 + arow) * K + (k0 + ac4));
    float4 b4 = *(const float4*)(W + (size_t)(k0 + bkk) * N + (n0 + bc4));
    As[ac4 + 0][arow] = a4.x;
    As[ac4 + 1][arow] = a4.y;
    As[ac4 + 2][arow] = a4.z;
    As[ac4 + 3][arow] = a4.w;
    *(float4*)&Bs[bkk][bc4] = b4;
    __syncthreads();
#pragma unroll
    for (int kk = 0; kk < 16; ++kk) {
      float4 av = *(const float4*)&As[kk][ty * 4];
      float4 bv = *(const float4*)&Bs[kk][tx * 4];
#pragma unroll
      for (int i = 0; i < 4; ++i) {
        float a = (i == 0) ? av.x : (i == 1) ? av.y : (i == 2) ? av.z : av.w;
        acc[i][0] = fmaf(a, bv.x, acc[i][0]);
        acc[i][1] = fmaf(a, bv.y, acc[i][1]);
        acc[i][2] = fmaf(a, bv.z, acc[i][2]);
        acc[i][3] = fmaf(a, bv.w, acc[i][3]);
      }
    }
    __syncthreads();
  }
  float4 bb = make_float4(0.f, 0.f, 0.f, 0.f);
  if (bias) bb = *(const float4*)(bias + n0 + tx * 4);
#pragma unroll
  for (int i = 0; i < 4; ++i) {
    size_t off = (size_t)(m0 + ty * 4 + i) * N + n0 + tx * 4;
    float4 o;
    o.x = acc[i][0] + bb.x;
    o.y = acc[i][1] + bb.y;
    o.z = acc[i][2] + bb.z;
    o.w = acc[i][3] + bb.w;
    *(float4*)(C + off) = o;
    if (Cbf) *(uint2*)(Cbf + off) = make_uint2(pk2(o.x, o.y), pk2(o.z, o.w));
  }
}

// -------- fused weight transpose+convert: WT[y][n][k] = bf16(W_y[k][n]) -----
__global__ __launch_bounds__(256) void wtrans6(const float* __restrict__ Wv,
                                               const float* __restrict__ Wm1,
                                               const float* __restrict__ Wm2,
                                               const float* __restrict__ Wo,
                                               u16* __restrict__ WT) {
  const size_t DD = (size_t)DIM * DIM;
  const int y = blockIdx.y;
  const float* src = (y == 0) ? Wv
                   : (y == 1) ? Wm1
                   : (y == 2) ? Wm1 + DD
                   : (y == 3) ? Wm2
                   : (y == 4) ? Wo
                              : Wo + DD;
  u16* dst = WT + (size_t)y * DD;
  int o = blockIdx.x * 256 + threadIdx.x;  // 65536 total, 4 outputs each
  int n = o >> 7;
  int k0 = (o & 127) * 4;
  float a0 = src[(size_t)(k0 + 0) * DIM + n];
  float a1 = src[(size_t)(k0 + 1) * DIM + n];
  float a2 = src[(size_t)(k0 + 2) * DIM + n];
  float a3 = src[(size_t)(k0 + 3) * DIM + n];
  ((uint2*)dst)[(n << 7) + (k0 >> 2)] = make_uint2(pk2(a0, a1), pk2(a2, a3));
}

// ---------------- bf16 MFMA GEMM: C[16384,512] = A[.,512] @ W[512,512] ------
// WT is [N][K] bf16 (pre-transposed). A fp32 converted in staging.
__global__ __launch_bounds__(256) void gemmbf(const float* __restrict__ A,
                                              const u16* __restrict__ WT,
                                              const float* __restrict__ bias,
                                              float* C, int accum) {
  __shared__ u16 As[128 * 32];   // [row][k] swizzled: slot ^= (row>>1)&3
  __shared__ u16 Bs[128 * 32];   // [col][k] swizzled
  const int tid = threadIdx.x;
  const int n0 = blockIdx.x * 128;
  const int m0 = blockIdx.y * 128;
  const int l = tid & 63, lr = l & 15, lu = l >> 4;
  const int wid = tid >> 6, wr = wid >> 1, wc = wid & 1;
  const int srow = tid >> 1, shalf = tid & 1;
  f32x4 acc[4][4] = {};
  for (int k0 = 0; k0 < 512; k0 += 32) {
    __syncthreads();
    {  // stage A: 16 fp32 -> 16 bf16
      const float4* a4 = (const float4*)(A + (size_t)(m0 + srow) * 512 + k0 + shalf * 16);
      float4 u0 = a4[0], u1 = a4[1], u2 = a4[2], u3 = a4[3];
      int sw = (srow >> 1) & 3;
      *(uint4*)&As[srow * 32 + ((shalf * 2 + 0) ^ sw) * 8] = pk8(u0, u1);
      *(uint4*)&As[srow * 32 + ((shalf * 2 + 1) ^ sw) * 8] = pk8(u2, u3);
    }
    {  // stage B: copy bf16
      const uint4* b4 = (const uint4*)(WT + (size_t)(n0 + srow) * 512 + k0 + shalf * 16);
      uint4 v0 = b4[0], v1 = b4[1];
      int sw = (srow >> 1) & 3;
      *(uint4*)&Bs[srow * 32 + ((shalf * 2 + 0) ^ sw) * 8] = v0;
      *(uint4*)&Bs[srow * 32 + ((shalf * 2 + 1) ^ sw) * 8] = v1;
    }
    __syncthreads();
    bf16x8 af[4], bf_[4];
#pragma unroll
    for (int fr = 0; fr < 4; ++fr) {
      int row = wr * 64 + fr * 16 + lr;
      af[fr] = *(const bf16x8*)&As[row * 32 + (lu ^ ((row >> 1) & 3)) * 8];
    }
#pragma unroll
    for (int fc = 0; fc < 4; ++fc) {
      int col = wc * 64 + fc * 16 + lr;
      bf_[fc] = *(const bf16x8*)&Bs[col * 32 + (lu ^ ((col >> 1) & 3)) * 8];
    }
#pragma unroll
    for (int fr = 0; fr < 4; ++fr)
#pragma unroll
      for (int fc = 0; fc < 4; ++fc)
        acc[fr][fc] = __builtin_amdgcn_mfma_f32_16x16x32_bf16(af[fr], bf_[fc], acc[fr][fc], 0, 0, 0);
  }
#pragma unroll
  for (int fr = 0; fr < 4; ++fr)
#pragma unroll
    for (int fc = 0; fc < 4; ++fc) {
      int col = n0 + wc * 64 + fc * 16 + lr;
      float bb = bias ? bias[col] : 0.f;
#pragma unroll
      for (int j = 0; j < 4; ++j) {
        int row = m0 + wr * 64 + fr * 16 + lu * 4 + j;
        size_t off = (size_t)row * 512 + col;
        float o = acc[fr][fc][j] + bb;
        if (accum) o += C[off];
        C[off] = o;
      }
    }
}

// -------- local message combine: g = 0.25*sum_w silu(A + bm1 + Bv[n-w]) -----
__global__ __launch_bounds__(256) void silu_combine(const float* A,
                                                    const float* Bv,
                                                    const float* bm1,
                                                    float* Gout) {
  size_t idx = (size_t)blockIdx.x * 256 + threadIdx.x;
  int r = (int)(idx >> 7);
  int c4 = (int)(idx & 127);
  int n = r & (NSEQ - 1);
  const float4* A4 = (const float4*)A;
  const float4* B4 = (const float4*)Bv;
  float4 a = A4[(size_t)r * 128 + c4];
  float4 bm = ((const float4*)bm1)[c4];
  float bx = a.x + bm.x, by = a.y + bm.y, bz = a.z + bm.z, bw = a.w + bm.w;
  float sx = 0.f, sy = 0.f, sz = 0.f, sw = 0.f;
#pragma unroll
  for (int w = 1; w <= 4; ++w) {
    float ex = bx, ey = by, ez = bz, ew = bw;
    if (n >= w) {
      float4 nb = B4[(size_t)(r - w) * 128 + c4];
      ex += nb.x; ey += nb.y; ez += nb.z; ew += nb.w;
    }
    sx += ex / (1.f + expf(-ex));
    sy += ey / (1.f + expf(-ey));
    sz += ez / (1.f + expf(-ez));
    sw += ew / (1.f + expf(-ew));
  }
  ((float4*)Gout)[(size_t)r * 128 + c4] =
      make_float4(0.25f * sx, 0.25f * sy, 0.25f * sz, 0.25f * sw);
}

// ---------------- MFMA candidate-gen + exact np rescore attention -----------
// Block = 32 queries of one batch, 256 thr (4 waves). 256-key tiles; K
// fragments loaded DIRECTLY from global bf16 K (no LDS staging, no k-loop
// barriers). Scores -> LDS -> per-(query,slice) top-16 (bf16 order) -> merged
// top-16 -> in-thread exact np-chain rescore -> exact top-8 + softmax + PV.
__global__ __launch_bounds__(256) void attn_mfma(const float* __restrict__ Qf,
                                                 const float* __restrict__ Kf,
                                                 const u16* __restrict__ Kbf,
                                                 const float* __restrict__ V,
                                                 float* __restrict__ G) {
  __shared__ union UA {
    u16 Qs[32 * 512];      // streaming phase (swizzled)
    u64 cand[256][16];     // candidate stash after streaming
  } uA;
  __shared__ float S[32][260];   // stride 260: score-write & scan <=2-way banks
  __shared__ int cidx[32][16];
  __shared__ u64 exkey[32][16];
  __shared__ float psm[32][8];
  __shared__ int pidx[32][8];

  const int tid = threadIdx.x;
  const int bid = blockIdx.x;
  const int b = bid & 3;
  const int h = bid >> 2;                        // 0..127
  const int qt = (h < 64) ? 2 * h : 255 - 2 * h; // load-balance pairing
  const int n0 = qt * 32;
  const size_t rb = (size_t)b * NSEQ;
  const float SCALE_F = 0.04419417382415922f;    // (float)(1/sqrt(512))

  const int l = tid & 63, lr = l & 15, lu = l >> 4;
  const int wid = tid >> 6;
  const int wkey = wid * 64;                     // 64-key range per wave

  // ---- stage Q block fp32->bf16, swizzled ----
  {
    int row = tid >> 3, part = tid & 7;
    const float4* src = (const float4*)(Qf + ((rb + n0 + row) << 9));
#pragma unroll
    for (int c = 0; c < 8; ++c) {
      int slot = part * 8 + c;
      float4 x = src[slot * 2], y = src[slot * 2 + 1];
      *(uint4*)&uA.Qs[row * 512 + (slot ^ (row & 7)) * 8] = pk8(x, y);
    }
  }
  __syncthreads();

  u64 best[16] = {};
  const int qi_s = tid >> 3, sl = tid & 7;
  const int nq = n0 + qi_s;

  const int nkt = (n0 + 32 + 255) >> 8;
  for (int kt = 0; kt < nkt; ++kt) {
    const int m0 = kt << 8;
    if (m0 + wkey <= n0 + 31) {  // wave has unmasked keys in this tile
      f32x4 acc[2][4] = {};
      const u16* kb = Kbf + ((rb + m0 + wkey) << 9);
#pragma unroll 4
      for (int k0 = 0; k0 < 512; k0 += 32) {
        bf16x8 af[2];
#pragma unroll
        for (int fq = 0; fq < 2; ++fq) {
          int row = fq * 16 + lr;
          af[fq] = *(const bf16x8*)&uA.Qs[row * 512 + (((k0 >> 3) + lu) ^ (row & 7)) * 8];
        }
#pragma unroll
        for (int fk = 0; fk < 4; ++fk) {
          bf16x8 bf = *(const bf16x8*)(kb + ((size_t)(fk * 16 + lr) << 9) + k0 + lu * 8);
          acc[0][fk] = __builtin_amdgcn_mfma_f32_16x16x32_bf16(af[0], bf, acc[0][fk], 0, 0, 0);
          acc[1][fk] = __builtin_amdgcn_mfma_f32_16x16x32_bf16(af[1], bf, acc[1][fk], 0, 0, 0);
        }
      }
#pragma unroll
      for (int fq = 0; fq < 2; ++fq)
#pragma unroll
        for (int fk = 0; fk < 4; ++fk)
#pragma unroll
          for (int j = 0; j < 4; ++j)
            S[fq * 16 + lu * 4 + j][wkey + fk * 16 + lr] = acc[fq][fk][j];
    }
    __syncthreads();
    // scan: strided cols (2-way banks), per-(query,slice) streaming top-16
#pragma unroll 4
    for (int j = 0; j < 32; ++j) {
      int c = sl + 8 * j;
      int m = m0 + c;
      if (m <= nq) insert_topN<16>(best, pack_key(S[qi_s][c], m));
    }
    __syncthreads();
  }

  // stash per-thread candidates (Qs region dead)
#pragma unroll
  for (int i = 0; i < 16; ++i) uA.cand[tid][i] = best[i];
  __syncthreads();

  // merge 8 slices -> per-query bf16 top-16 candidate indices
  if (tid < 32) {
    u64 mb[16] = {};
    for (int s2 = 0; s2 < 8; ++s2)
#pragma unroll
      for (int t2 = 0; t2 < 16; ++t2) insert_topN<16>(mb, uA.cand[tid * 8 + s2][t2]);
#pragma unroll
    for (int i = 0; i < 16; ++i)
      cidx[tid][i] = (mb[i] != 0ULL) ? (int)(~(u32)mb[i]) : -1;
  }
  __syncthreads();

  // ---- exact np-chain rescore of <=16 candidates per query ----
  {
    const int qi = tid >> 3, cp = tid & 7;
    const float4* q4 = (const float4*)(Qf + ((rb + n0 + qi) << 9));
#pragma unroll
    for (int cc = 0; cc < 2; ++cc) {
      int c = cp * 2 + cc;
      int ci = cidx[qi][c];
      u64 key = 0;
      if (ci >= 0) {
        const float4* k4 = (const float4*)(Kf + ((rb + ci) << 9));
        float p[16] = {};
#pragma unroll 4
        for (int t = 0; t < 128; ++t) {
          float4 qv = q4[t], kv = k4[t];
          int j = (t & 3) * 4;
          p[j + 0] = fmaf(qv.x, kv.x, p[j + 0]);
          p[j + 1] = fmaf(qv.y, kv.y, p[j + 1]);
          p[j + 2] = fmaf(qv.z, kv.z, p[j + 2]);
          p[j + 3] = fmaf(qv.w, kv.w, p[j + 3]);
        }
#pragma unroll
        for (int s = 8; s >= 1; s >>= 1)
#pragma unroll
          for (int jj = 0; jj < 8; ++jj)
            if (jj < s) p[jj] = p[jj] + p[jj + s];
        key = pack_key(p[0] * SCALE_F, ci);
      }
      exkey[qi][c] = key;
    }
  }
  __syncthreads();

  // ---- exact top-8 + np softmax ----
  if (tid < 32) {
    u64 mb[8] = {};
#pragma unroll
    for (int t2 = 0; t2 < 16; ++t2) insert_top8(mb, exkey[tid][t2]);
    float vmax = decode_val(mb[0]);
    float e[8];
#pragma unroll
    for (int i = 0; i < 8; ++i)
      e[i] = (mb[i] != 0ULL) ? expf(decode_val(mb[i]) - vmax) : 0.f;
    float s01 = e[0] + e[1], s23 = e[2] + e[3];
    float s45 = e[4] + e[5], s67 = e[6] + e[7];
    float ssum = (s01 + s23) + (s45 + s67);  // np pairwise-8 tree
#pragma unroll
    for (int i = 0; i < 8; ++i) {
      psm[tid][i] = e[i] / ssum;
      pidx[tid][i] = (mb[i] != 0ULL) ? (int)(~(u32)mb[i]) : 0;
    }
  }
  __syncthreads();

  // ---- PV gather: 8 threads per query, 64 dims each ----
  {
    const int qi = tid >> 3, seg = tid & 7;
    float pp[8];
    int ix[8];
#pragma unroll
    for (int i = 0; i < 8; ++i) { pp[i] = psm[qi][i]; ix[i] = pidx[qi][i]; }
    const float4* V4 = (const float4*)V;
    float4* G4 = (float4*)G;
    const size_t ob = ((rb + n0 + qi) << 7) + seg * 16;
#pragma unroll
    for (int it = 0; it < 16; ++it) {
      float4 a = make_float4(0.f, 0.f, 0.f, 0.f);
#pragma unroll
      for (int i = 0; i < 8; ++i) {
        float4 vv = V4[((rb + ix[i]) << 7) + seg * 16 + it];
        a.x = fmaf(pp[i], vv.x, a.x);
        a.y = fmaf(pp[i], vv.y, a.y);
        a.z = fmaf(pp[i], vv.z, a.z);
        a.w = fmaf(pp[i], vv.w, a.w);
      }
      G4[ob + it] = a;
    }
  }
}

extern "C" void kernel_launch(void* const* d_in, const int* in_sizes, int n_in,
                              void* d_out, int out_size, void* d_ws, size_t ws_size,
                              hipStream_t stream) {
  const float* mu = (const float*)d_in[0];
  const float* Wq = (const float*)d_in[1];
  const float* bq = (const float*)d_in[2];
  const float* Wk = (const float*)d_in[3];
  const float* bk = (const float*)d_in[4];
  const float* Wv = (const float*)d_in[5];
  const float* bv = (const float*)d_in[6];
  const float* Wm1 = (const float*)d_in[7];
  const float* bm1 = (const float*)d_in[8];
  const float* Wm2 = (const float*)d_in[9];
  const float* bm2 = (const float*)d_in[10];
  const float* Wo = (const float*)d_in[11];
  const float* bo = (const float*)d_in[12];
  float* out = (float*)d_out;

  float* ws = (float*)d_ws;
  const size_t RD = (size_t)ROWS * DIM;
  const size_t DD = (size_t)DIM * DIM;
  float* X1 = ws;            // q           -> later A, g
  float* X2 = X1 + RD;       // k           -> later Bv
  float* X3 = X2 + RD;       // v           -> later local
  float* X4 = X3 + RD;       // global msgs
  u16* Kbf = (u16*)(X4 + RD);          // RD bf16
  u16* WT = Kbf + RD;                  // 6 x 512x512 bf16
  u16* WvT = WT;
  u16* Wm1aT = WT + DD;
  u16* Wm1bT = WT + 2 * DD;
  u16* Wm2T = WT + 3 * DD;
  u16* WoTT = WT + 4 * DD;
  u16* WoBT = WT + 5 * DD;

  dim3 blk(256);
  dim3 gex(DIM / 64, ROWS / 64);
  dim3 gbf(DIM / 128, ROWS / 128);

  // all 6 weight transposes in one launch
  wtrans6<<<dim3(256, 6), blk, 0, stream>>>(Wv, Wm1, Wm2, Wo, WT);

  // q,k: exact-chain fp32 (np-bit-exact, feeds selection); k also emits bf16
  gemm64f<<<gex, blk, 0, stream>>>(mu, Wq, bq, X1, (u16*)nullptr, ROWS, DIM, DIM);
  gemm64f<<<gex, blk, 0, stream>>>(mu, Wk, bk, X2, Kbf, ROWS, DIM, DIM);

  // v (bf16 MFMA; value-path precision is ample)
  gemmbf<<<gbf, blk, 0, stream>>>(mu, WvT, bv, X3, 0);

  // sparse causal attention -> X4
  attn_mfma<<<dim3(512), blk, 0, stream>>>(X1, X2, Kbf, X3, X4);

  // local path (q,k,v buffers now dead -> reuse)
  gemmbf<<<gbf, blk, 0, stream>>>(mu, Wm1aT, (const float*)nullptr, X1, 0);
  gemmbf<<<gbf, blk, 0, stream>>>(mu, Wm1bT, (const float*)nullptr, X2, 0);
  silu_combine<<<dim3(ROWS * 128 / 256), blk, 0, stream>>>(X1, X2, bm1, X1);
  gemmbf<<<gbf, blk, 0, stream>>>(X1, Wm2T, bm2, X3, 0);

  // out = local @ Wo_top + bo ; out += global @ Wo_bot
  gemmbf<<<gbf, blk, 0, stream>>>(X3, WoTT, bo, out, 0);
  gemmbf<<<gbf, blk, 0, stream>>>(X4, WoBT, (const float*)nullptr, out, 1);
}

// Round 7
// 896.354 us; speedup vs baseline: 2.2913x; 1.1542x over previous
//
#include <hip/hip_runtime.h>
#include <math.h>

#define DIM 512
#define NSEQ 4096
#define BATCH 4
#define ROWS (BATCH * NSEQ)   // 16384

typedef unsigned long long u64;
typedef unsigned int u32;
typedef unsigned short u16;
typedef __attribute__((ext_vector_type(8))) short bf16x8;
typedef __attribute__((ext_vector_type(4))) float f32x4;

// ---------------- bf16 helpers (RNE) ----------------
__device__ __forceinline__ u32 to_bf16(float f) {
  u32 x = __float_as_uint(f);
  return (x + 0x7fffu + ((x >> 16) & 1u)) >> 16;
}
__device__ __forceinline__ u32 pk2(float a, float b) {
  return to_bf16(a) | (to_bf16(b) << 16);
}
__device__ __forceinline__ uint4 pk8(float4 a, float4 b) {
  return make_uint4(pk2(a.x, a.y), pk2(a.z, a.w), pk2(b.x, b.y), pk2(b.z, b.w));
}

// ---------------- top-N helpers (packed u64 keys) ----------------
// key = ordered_float(score)<<32 | ~index : larger key == larger score; exact
// fp32 ties break toward LOWER index (= np stable top_k). key==0 empty.
__device__ __forceinline__ void insert_top8(u64 (&a)[8], u64 key) {
  if (key <= a[7]) return;
  a[7] = key;
#pragma unroll
  for (int i = 7; i > 0; --i) {
    u64 x = a[i - 1], y = a[i];
    u64 hi = x > y ? x : y;
    u64 lo = x > y ? y : x;
    a[i - 1] = hi;
    a[i] = lo;
  }
}
template<int NN>
__device__ __forceinline__ void insert_topN(u64 (&a)[NN], u64 key) {
  if (key <= a[NN - 1]) return;
  a[NN - 1] = key;
#pragma unroll
  for (int i = NN - 1; i > 0; --i) {
    u64 x = a[i - 1], y = a[i];
    u64 hi = x > y ? x : y;
    u64 lo = x > y ? y : x;
    a[i - 1] = hi;
    a[i] = lo;
  }
}
__device__ __forceinline__ float decode_val(u64 key) {
  u32 ord = (u32)(key >> 32);
  u32 s = (ord & 0x80000000u) ? (ord ^ 0x80000000u) : ~ord;
  return __uint_as_float(s);
}
__device__ __forceinline__ u64 pack_key(float v, int m) {
  u32 sb = __float_as_uint(v);
  u32 ord = sb ^ ((sb >> 31) ? 0xFFFFFFFFu : 0x80000000u);
  return ((u64)ord << 32) | (u32)(~(u32)m);
}

// ------- exact-chain fp32 GEMM (np/OpenBLAS-bit-exact) — q,k only -------
// Optional Cbf: also emit bf16(o) (fuses the k->bf16 convert pass).
__global__ __launch_bounds__(256) void gemm64f(const float* __restrict__ X,
                                               const float* __restrict__ W,
                                               const float* __restrict__ bias,
                                               float* C, u16* Cbf,
                                               int M, int N, int K) {
  __shared__ float As[16][68];
  __shared__ float Bs[16][68];
  const int tid = threadIdx.x;
  const int tx = tid & 15, ty = tid >> 4;
  const int n0 = blockIdx.x * 64;
  const int m0 = blockIdx.y * 64;
  const int arow = tid >> 2, ac4 = (tid & 3) * 4;
  const int bkk = tid >> 4, bc4 = (tid & 15) * 4;
  float acc[4][4] = {};
  for (int k0 = 0; k0 < K; k0 += 16) {
    float4 a4 = *(const float4*)(X + (size_t)(m0 + arow) * K + (k0 + ac4));
    float4 b4 = *(const float4*)(W + (size_t)(k0 + bkk) * N + (n0 + bc4));
    As[ac4 + 0][arow] = a4.x;
    As[ac4 + 1][arow] = a4.y;
    As[ac4 + 2][arow] = a4.z;
    As[ac4 + 3][arow] = a4.w;
    *(float4*)&Bs[bkk][bc4] = b4;
    __syncthreads();
#pragma unroll
    for (int kk = 0; kk < 16; ++kk) {
      float4 av = *(const float4*)&As[kk][ty * 4];
      float4 bv = *(const float4*)&Bs[kk][tx * 4];
#pragma unroll
      for (int i = 0; i < 4; ++i) {
        float a = (i == 0) ? av.x : (i == 1) ? av.y : (i == 2) ? av.z : av.w;
        acc[i][0] = fmaf(a, bv.x, acc[i][0]);
        acc[i][1] = fmaf(a, bv.y, acc[i][1]);
        acc[i][2] = fmaf(a, bv.z, acc[i][2]);
        acc[i][3] = fmaf(a, bv.w, acc[i][3]);
      }
    }
    __syncthreads();
  }
  float4 bb = make_float4(0.f, 0.f, 0.f, 0.f);
  if (bias) bb = *(const float4*)(bias + n0 + tx * 4);
#pragma unroll
  for (int i = 0; i < 4; ++i) {
    size_t off = (size_t)(m0 + ty * 4 + i) * N + n0 + tx * 4;
    float4 o;
    o.x = acc[i][0] + bb.x;
    o.y = acc[i][1] + bb.y;
    o.z = acc[i][2] + bb.z;
    o.w = acc[i][3] + bb.w;
    *(float4*)(C + off) = o;
    if (Cbf) *(uint2*)(Cbf + off) = make_uint2(pk2(o.x, o.y), pk2(o.z, o.w));
  }
}

// -------- fused weight transpose+convert: WT[y][n][k] = bf16(W_y[k][n]) -----
__global__ __launch_bounds__(256) void wtrans6(const float* __restrict__ Wv,
                                               const float* __restrict__ Wm1,
                                               const float* __restrict__ Wm2,
                                               const float* __restrict__ Wo,
                                               u16* __restrict__ WT) {
  const size_t DD = (size_t)DIM * DIM;
  const int y = blockIdx.y;
  const float* src = (y == 0) ? Wv
                   : (y == 1) ? Wm1
                   : (y == 2) ? Wm1 + DD
                   : (y == 3) ? Wm2
                   : (y == 4) ? Wo
                              : Wo + DD;
  u16* dst = WT + (size_t)y * DD;
  int o = blockIdx.x * 256 + threadIdx.x;  // 65536 total, 4 outputs each
  int n = o >> 7;
  int k0 = (o & 127) * 4;
  float a0 = src[(size_t)(k0 + 0) * DIM + n];
  float a1 = src[(size_t)(k0 + 1) * DIM + n];
  float a2 = src[(size_t)(k0 + 2) * DIM + n];
  float a3 = src[(size_t)(k0 + 3) * DIM + n];
  ((uint2*)dst)[(n << 7) + (k0 >> 2)] = make_uint2(pk2(a0, a1), pk2(a2, a3));
}

// ---------------- bf16 MFMA GEMM: C[16384,512] = A[.,512] @ W[512,512] ------
// WT is [N][K] bf16 (pre-transposed). A fp32 converted in staging.
__global__ __launch_bounds__(256) void gemmbf(const float* __restrict__ A,
                                              const u16* __restrict__ WT,
                                              const float* __restrict__ bias,
                                              float* C, int accum) {
  __shared__ u16 As[128 * 32];   // [row][k] swizzled: slot ^= (row>>1)&3
  __shared__ u16 Bs[128 * 32];   // [col][k] swizzled
  const int tid = threadIdx.x;
  const int n0 = blockIdx.x * 128;
  const int m0 = blockIdx.y * 128;
  const int l = tid & 63, lr = l & 15, lu = l >> 4;
  const int wid = tid >> 6, wr = wid >> 1, wc = wid & 1;
  const int srow = tid >> 1, shalf = tid & 1;
  f32x4 acc[4][4] = {};
  for (int k0 = 0; k0 < 512; k0 += 32) {
    __syncthreads();
    {  // stage A: 16 fp32 -> 16 bf16
      const float4* a4 = (const float4*)(A + (size_t)(m0 + srow) * 512 + k0 + shalf * 16);
      float4 u0 = a4[0], u1 = a4[1], u2 = a4[2], u3 = a4[3];
      int sw = (srow >> 1) & 3;
      *(uint4*)&As[srow * 32 + ((shalf * 2 + 0) ^ sw) * 8] = pk8(u0, u1);
      *(uint4*)&As[srow * 32 + ((shalf * 2 + 1) ^ sw) * 8] = pk8(u2, u3);
    }
    {  // stage B: copy bf16
      const uint4* b4 = (const uint4*)(WT + (size_t)(n0 + srow) * 512 + k0 + shalf * 16);
      uint4 v0 = b4[0], v1 = b4[1];
      int sw = (srow >> 1) & 3;
      *(uint4*)&Bs[srow * 32 + ((shalf * 2 + 0) ^ sw) * 8] = v0;
      *(uint4*)&Bs[srow * 32 + ((shalf * 2 + 1) ^ sw) * 8] = v1;
    }
    __syncthreads();
    bf16x8 af[4], bf_[4];
#pragma unroll
    for (int fr = 0; fr < 4; ++fr) {
      int row = wr * 64 + fr * 16 + lr;
      af[fr] = *(const bf16x8*)&As[row * 32 + (lu ^ ((row >> 1) & 3)) * 8];
    }
#pragma unroll
    for (int fc = 0; fc < 4; ++fc) {
      int col = wc * 64 + fc * 16 + lr;
      bf_[fc] = *(const bf16x8*)&Bs[col * 32 + (lu ^ ((col >> 1) & 3)) * 8];
    }
#pragma unroll
    for (int fr = 0; fr < 4; ++fr)
#pragma unroll
      for (int fc = 0; fc < 4; ++fc)
        acc[fr][fc] = __builtin_amdgcn_mfma_f32_16x16x32_bf16(af[fr], bf_[fc], acc[fr][fc], 0, 0, 0);
  }
#pragma unroll
  for (int fr = 0; fr < 4; ++fr)
#pragma unroll
    for (int fc = 0; fc < 4; ++fc) {
      int col = n0 + wc * 64 + fc * 16 + lr;
      float bb = bias ? bias[col] : 0.f;
#pragma unroll
      for (int j = 0; j < 4; ++j) {
        int row = m0 + wr * 64 + fr * 16 + lu * 4 + j;
        size_t off = (size_t)row * 512 + col;
        float o = acc[fr][fc][j] + bb;
        if (accum) o += C[off];
        C[off] = o;
      }
    }
}

// -------- local message combine: g = 0.25*sum_w silu(A + bm1 + Bv[n-w]) -----
__global__ __launch_bounds__(256) void silu_combine(const float* A,
                                                    const float* Bv,
                                                    const float* bm1,
                                                    float* Gout) {
  size_t idx = (size_t)blockIdx.x * 256 + threadIdx.x;
  int r = (int)(idx >> 7);
  int c4 = (int)(idx & 127);
  int n = r & (NSEQ - 1);
  const float4* A4 = (const float4*)A;
  const float4* B4 = (const float4*)Bv;
  float4 a = A4[(size_t)r * 128 + c4];
  float4 bm = ((const float4*)bm1)[c4];
  float bx = a.x + bm.x, by = a.y + bm.y, bz = a.z + bm.z, bw = a.w + bm.w;
  float sx = 0.f, sy = 0.f, sz = 0.f, sw = 0.f;
#pragma unroll
  for (int w = 1; w <= 4; ++w) {
    float ex = bx, ey = by, ez = bz, ew = bw;
    if (n >= w) {
      float4 nb = B4[(size_t)(r - w) * 128 + c4];
      ex += nb.x; ey += nb.y; ez += nb.z; ew += nb.w;
    }
    sx += ex / (1.f + expf(-ex));
    sy += ey / (1.f + expf(-ey));
    sz += ez / (1.f + expf(-ez));
    sw += ew / (1.f + expf(-ew));
  }
  ((float4*)Gout)[(size_t)r * 128 + c4] =
      make_float4(0.25f * sx, 0.25f * sy, 0.25f * sz, 0.25f * sw);
}

// ---------------- MFMA candidate-gen + exact np rescore attention -----------
// Block = 16 queries of one batch, 4 waves. Swapped-operand MFMA (A=K, B=Q):
// each lane holds 16 scores of ONE query (col=lane&15) per tile and keeps a
// per-thread top-8 candidate list IN REGISTERS — no score LDS, no barriers in
// the streaming loop. Waves stream interleaved 64-key tiles independently.
// Merge 16 lists/query -> bf16 top-16 -> exact np-chain rescore -> exact
// top-8 + np softmax + PV. XCD-aware: batch = (bid&7)>>1 keeps each XCD's K
// slice (4 MB bf16) L2-resident.
__global__ __launch_bounds__(256, 4) void attn_mfma(const float* __restrict__ Qf,
                                                    const float* __restrict__ Kf,
                                                    const u16* __restrict__ Kbf,
                                                    const float* __restrict__ V,
                                                    float* __restrict__ G) {
  __shared__ union UA {
    u16 Qs[16 * 512];      // streaming phase (swizzled)     16 KB
    u64 cand[256][8];      // candidate stash after streaming 16 KB
  } uA;
  __shared__ int cidx[16][16];
  __shared__ u64 exkey[16][16];
  __shared__ float psm[16][8];
  __shared__ int pidx[16][8];

  const int tid = threadIdx.x;
  const int bid = blockIdx.x;            // 1024 blocks
  const int xcd = bid & 7;
  const int b = xcd >> 1;                // 2 XCDs per batch
  const int par = xcd & 1;
  const int sub = bid >> 3;              // 0..127
  const int qt = 2 * (127 - sub) + par;  // heavy tiles dispatched first
  const int n0 = qt * 16;
  const size_t rb = (size_t)b * NSEQ;
  const float SCALE_F = 0.04419417382415922f;  // (float)(1/sqrt(512))

  const int l = tid & 63, lr = l & 15, lu = l >> 4;
  const int wid = tid >> 6;

  // ---- stage Q block (16 rows x 512) fp32->bf16, swizzled ----
  {
    int row = tid >> 4, part = tid & 15;
    const float4* src = (const float4*)(Qf + ((rb + n0 + row) << 9));
#pragma unroll
    for (int c = 0; c < 4; ++c) {
      int slot = part * 4 + c;
      float4 x = src[slot * 2], y = src[slot * 2 + 1];
      *(uint4*)&uA.Qs[row * 512 + (slot ^ (row & 7)) * 8] = pk8(x, y);
    }
  }
  __syncthreads();

  u64 best[8] = {};
  const int nq = n0 + lr;   // this lane's query row

  // ---- barrier-free streaming: wave wid takes 64-key tiles kt = wid, wid+4, ...
  const int nkt = (n0 + 16 + 63) >> 6;
  for (int kt = wid; kt < nkt; kt += 4) {
    const int m0 = kt << 6;
    f32x4 acc[4] = {};
    const u16* kb = Kbf + ((rb + m0) << 9);
#pragma unroll 4
    for (int k0 = 0; k0 < 512; k0 += 32) {
      bf16x8 qf = *(const bf16x8*)&uA.Qs[lr * 512 + ((((k0 >> 3) + lu)) ^ (lr & 7)) * 8];
#pragma unroll
      for (int fk = 0; fk < 4; ++fk) {
        bf16x8 kf = *(const bf16x8*)(kb + ((size_t)(fk * 16 + lr) << 9) + k0 + lu * 8);
        acc[fk] = __builtin_amdgcn_mfma_f32_16x16x32_bf16(kf, qf, acc[fk], 0, 0, 0);
      }
    }
    // C[key][query]: this lane holds query=lr, key = m0 + fk*16 + lu*4 + j
#pragma unroll
    for (int fk = 0; fk < 4; ++fk)
#pragma unroll
      for (int j = 0; j < 4; ++j) {
        int m = m0 + fk * 16 + lu * 4 + j;
        if (m <= nq) insert_top8(best, pack_key(acc[fk][j], m));
      }
  }

  __syncthreads();   // all waves done reading Qs
#pragma unroll
  for (int i = 0; i < 8; ++i) uA.cand[tid][i] = best[i];
  __syncthreads();

  // ---- merge 16 per-thread lists per query -> bf16 top-16 candidates ----
  if (tid < 16) {
    u64 mb[16] = {};
    for (int w = 0; w < 4; ++w)
      for (int u = 0; u < 4; ++u) {
        const u64* cl = uA.cand[w * 64 + u * 16 + tid];
#pragma unroll
        for (int i = 0; i < 8; ++i) insert_topN<16>(mb, cl[i]);
      }
#pragma unroll
    for (int i = 0; i < 16; ++i)
      cidx[tid][i] = (mb[i] != 0ULL) ? (int)(~(u32)mb[i]) : -1;
  }
  __syncthreads();

  // ---- exact np-chain rescore: 1 candidate per thread ----
  {
    const int qi = tid >> 4, c = tid & 15;
    int ci = cidx[qi][c];
    u64 key = 0;
    if (ci >= 0) {
      const float4* q4 = (const float4*)(Qf + ((rb + n0 + qi) << 9));
      const float4* k4 = (const float4*)(Kf + ((rb + ci) << 9));
      float p[16] = {};
#pragma unroll 4
      for (int t = 0; t < 128; ++t) {
        float4 qv = q4[t], kv = k4[t];
        int j = (t & 3) * 4;
        p[j + 0] = fmaf(qv.x, kv.x, p[j + 0]);
        p[j + 1] = fmaf(qv.y, kv.y, p[j + 1]);
        p[j + 2] = fmaf(qv.z, kv.z, p[j + 2]);
        p[j + 3] = fmaf(qv.w, kv.w, p[j + 3]);
      }
#pragma unroll
      for (int s = 8; s >= 1; s >>= 1)
#pragma unroll
        for (int jj = 0; jj < 8; ++jj)
          if (jj < s) p[jj] = p[jj] + p[jj + s];
      key = pack_key(p[0] * SCALE_F, ci);
    }
    exkey[qi][c] = key;
  }
  __syncthreads();

  // ---- exact top-8 + np softmax ----
  if (tid < 16) {
    u64 mb[8] = {};
#pragma unroll
    for (int t2 = 0; t2 < 16; ++t2) insert_top8(mb, exkey[tid][t2]);
    float vmax = decode_val(mb[0]);
    float e[8];
#pragma unroll
    for (int i = 0; i < 8; ++i)
      e[i] = (mb[i] != 0ULL) ? expf(decode_val(mb[i]) - vmax) : 0.f;
    float s01 = e[0] + e[1], s23 = e[2] + e[3];
    float s45 = e[4] + e[5], s67 = e[6] + e[7];
    float ssum = (s01 + s23) + (s45 + s67);  // np pairwise-8 tree
#pragma unroll
    for (int i = 0; i < 8; ++i) {
      psm[tid][i] = e[i] / ssum;
      pidx[tid][i] = (mb[i] != 0ULL) ? (int)(~(u32)mb[i]) : 0;
    }
  }
  __syncthreads();

  // ---- PV gather: 16 threads per query, 32 dims each ----
  {
    const int qi = tid >> 4, seg = tid & 15;
    float pp[8];
    int ix[8];
#pragma unroll
    for (int i = 0; i < 8; ++i) { pp[i] = psm[qi][i]; ix[i] = pidx[qi][i]; }
    const float4* V4 = (const float4*)V;
    float4* G4 = (float4*)G;
    const size_t ob = ((rb + n0 + qi) << 7) + seg * 8;
#pragma unroll
    for (int it = 0; it < 8; ++it) {
      float4 a = make_float4(0.f, 0.f, 0.f, 0.f);
#pragma unroll
      for (int i = 0; i < 8; ++i) {
        float4 vv = V4[((rb + ix[i]) << 7) + seg * 8 + it];
        a.x = fmaf(pp[i], vv.x, a.x);
        a.y = fmaf(pp[i], vv.y, a.y);
        a.z = fmaf(pp[i], vv.z, a.z);
        a.w = fmaf(pp[i], vv.w, a.w);
      }
      G4[ob + it] = a;
    }
  }
}

extern "C" void kernel_launch(void* const* d_in, const int* in_sizes, int n_in,
                              void* d_out, int out_size, void* d_ws, size_t ws_size,
                              hipStream_t stream) {
  const float* mu = (const float*)d_in[0];
  const float* Wq = (const float*)d_in[1];
  const float* bq = (const float*)d_in[2];
  const float* Wk = (const float*)d_in[3];
  const float* bk = (const float*)d_in[4];
  const float* Wv = (const float*)d_in[5];
  const float* bv = (const float*)d_in[6];
  const float* Wm1 = (const float*)d_in[7];
  const float* bm1 = (const float*)d_in[8];
  const float* Wm2 = (const float*)d_in[9];
  const float* bm2 = (const float*)d_in[10];
  const float* Wo = (const float*)d_in[11];
  const float* bo = (const float*)d_in[12];
  float* out = (float*)d_out;

  float* ws = (float*)d_ws;
  const size_t RD = (size_t)ROWS * DIM;
  const size_t DD = (size_t)DIM * DIM;
  float* X1 = ws;            // q           -> later A, g
  float* X2 = X1 + RD;       // k           -> later Bv
  float* X3 = X2 + RD;       // v           -> later local
  float* X4 = X3 + RD;       // global msgs
  u16* Kbf = (u16*)(X4 + RD);          // RD bf16
  u16* WT = Kbf + RD;                  // 6 x 512x512 bf16
  u16* WvT = WT;
  u16* Wm1aT = WT + DD;
  u16* Wm1bT = WT + 2 * DD;
  u16* Wm2T = WT + 3 * DD;
  u16* WoTT = WT + 4 * DD;
  u16* WoBT = WT + 5 * DD;

  dim3 blk(256);
  dim3 gex(DIM / 64, ROWS / 64);
  dim3 gbf(DIM / 128, ROWS / 128);

  // all 6 weight transposes in one launch
  wtrans6<<<dim3(256, 6), blk, 0, stream>>>(Wv, Wm1, Wm2, Wo, WT);

  // q,k: exact-chain fp32 (np-bit-exact, feeds selection); k also emits bf16
  gemm64f<<<gex, blk, 0, stream>>>(mu, Wq, bq, X1, (u16*)nullptr, ROWS, DIM, DIM);
  gemm64f<<<gex, blk, 0, stream>>>(mu, Wk, bk, X2, Kbf, ROWS, DIM, DIM);

  // v (bf16 MFMA; value-path precision is ample)
  gemmbf<<<gbf, blk, 0, stream>>>(mu, WvT, bv, X3, 0);

  // sparse causal attention -> X4
  attn_mfma<<<dim3(1024), blk, 0, stream>>>(X1, X2, Kbf, X3, X4);

  // local path (q,k,v buffers now dead -> reuse)
  gemmbf<<<gbf, blk, 0, stream>>>(mu, Wm1aT, (const float*)nullptr, X1, 0);
  gemmbf<<<gbf, blk, 0, stream>>>(mu, Wm1bT, (const float*)nullptr, X2, 0);
  silu_combine<<<dim3(ROWS * 128 / 256), blk, 0, stream>>>(X1, X2, bm1, X1);
  gemmbf<<<gbf, blk, 0, stream>>>(X1, Wm2T, bm2, X3, 0);

  // out = local @ Wo_top + bo ; out += global @ Wo_bot
  gemmbf<<<gbf, blk, 0, stream>>>(X3, WoTT, bo, out, 0);
  gemmbf<<<gbf, blk, 0, stream>>>(X4, WoBT, (const float*)nullptr, out, 1);
}